// Round 6
// baseline (1402.112 us; speedup 1.0000x reference)
//
#include <hip/hip_runtime.h>
#include <hip/hip_bf16.h>

#define NN 50000
#define CC 64
#define GG 3
#define EE 1200000
#define LL 2
#define DD 256
#define HH 256
#define NCHUNK 196          // ceil(NN/256) for row_start scan
#define NB 196              // dst buckets of 256 nodes
#define NSLICE 8
#define NSTAGE (GG * NB * NSLICE)   // 4704
#define NBLK 293            // ceil(EE/4096) edge chunks per graph

// Staged edge record (8B): x = bf16(e0)<<16 | bf16(e1); y = src<<16 | dst_local.
// Final per-layer packed word (4B): bf16(a)<<16 | src  (src < 2^16).

__device__ __forceinline__ ushort f2bf(float f) {
    unsigned b = __float_as_uint(f);
    return (ushort)((b + 0x7fffu + ((b >> 16) & 1u)) >> 16);
}
__device__ __forceinline__ float bf2f(unsigned u) {
    return __uint_as_float(u << 16);
}
// order-preserving float<->uint for atomicMax
__device__ __forceinline__ unsigned fenc(float f) {
    unsigned u = __float_as_uint(f);
    return (u & 0x80000000u) ? ~u : (u | 0x80000000u);
}
__device__ __forceinline__ float fdec(unsigned u) {
    u = (u & 0x80000000u) ? (u & 0x7fffffffu) : ~u;
    return __uint_as_float(u);
}

// ---------------------------------------------------------------------------
// GEMM: C[M,Nc] = act(A[M,K] @ B[K,Nc] + bias), fp32, 64x64 tile, 4x4 micro
// ---------------------------------------------------------------------------
__global__ __launch_bounds__(256) void gemm_kernel(
    const float* __restrict__ A, const float* __restrict__ B,
    const float* __restrict__ bias, float* __restrict__ Cout,
    int M, int Nc, int K, int do_relu)
{
    __shared__ float As[16][68];
    __shared__ float Bs[16][64];
    int tid = threadIdx.x;
    int tx = tid & 15;
    int ty = tid >> 4;
    int m0 = blockIdx.x * 64;
    int n0 = blockIdx.y * 64;
    float acc[4][4] = {};

    for (int k0 = 0; k0 < K; k0 += 16) {
        {
            int kk = tid & 15;
            int mm = tid >> 4;
            #pragma unroll
            for (int i = 0; i < 4; i++) {
                int m = m0 + mm + i * 16;
                float v = (m < M) ? A[(size_t)m * K + k0 + kk] : 0.f;
                As[kk][mm + i * 16] = v;
            }
        }
        {
            int nn = tid & 63;
            int kk = tid >> 6;
            #pragma unroll
            for (int i = 0; i < 4; i++) {
                Bs[kk + i * 4][nn] = B[(size_t)(k0 + kk + i * 4) * Nc + n0 + nn];
            }
        }
        __syncthreads();
        #pragma unroll
        for (int kk = 0; kk < 16; kk++) {
            float4 a4 = *(const float4*)&As[kk][ty * 4];
            float4 b4 = *(const float4*)&Bs[kk][tx * 4];
            acc[0][0] += a4.x * b4.x; acc[0][1] += a4.x * b4.y;
            acc[0][2] += a4.x * b4.z; acc[0][3] += a4.x * b4.w;
            acc[1][0] += a4.y * b4.x; acc[1][1] += a4.y * b4.y;
            acc[1][2] += a4.y * b4.z; acc[1][3] += a4.y * b4.w;
            acc[2][0] += a4.z * b4.x; acc[2][1] += a4.z * b4.y;
            acc[2][2] += a4.z * b4.z; acc[2][3] += a4.z * b4.w;
            acc[3][0] += a4.w * b4.x; acc[3][1] += a4.w * b4.y;
            acc[3][2] += a4.w * b4.z; acc[3][3] += a4.w * b4.w;
        }
        __syncthreads();
    }
    #pragma unroll
    for (int i = 0; i < 4; i++) {
        int m = m0 + ty * 4 + i;
        if (m >= M) continue;
        #pragma unroll
        for (int j = 0; j < 4; j++) {
            int n = n0 + tx * 4 + j;
            float v = acc[i][j] + bias[n];
            if (do_relu) v = fmaxf(v, 0.f);
            Cout[(size_t)m * Nc + n] = v;
        }
    }
}

// ---------------------------------------------------------------------------
// fp32 -> bf16 table conversion (vectorized 4-wide)
// ---------------------------------------------------------------------------
__global__ void cvt_kernel(const float* __restrict__ in, ushort* __restrict__ out, int n4)
{
    int i = blockIdx.x * blockDim.x + threadIdx.x;
    if (i >= n4) return;
    float4 f = ((const float4*)in)[i];
    ushort4 u;
    u.x = f2bf(f.x); u.y = f2bf(f.y); u.z = f2bf(f.z); u.w = f2bf(f.w);
    ((ushort4*)out)[i] = u;
}

// ---------------------------------------------------------------------------
// Histogram: per-node counts (row_start) + per-(g,bucket,slice) counts
// slice = (e >> 12) & 7  — deterministic from edge index, matches binA chunks.
// ---------------------------------------------------------------------------
__global__ void hist_kernel(const int* __restrict__ dst, int* __restrict__ counts,
                            int* __restrict__ stage_cnt)
{
    int idx = blockIdx.x * blockDim.x + threadIdx.x;
    if (idx >= GG * EE) return;
    int g = idx / EE;
    int e = idx - g * EE;
    int d = dst[idx];
    atomicAdd(&counts[g * NN + d], 1);
    int slice = (e >> 12) & 7;
    int bucket = d >> 8;
    atomicAdd(&stage_cnt[(((g * NB + bucket) << 3) | slice)], 1);
}

// ---------------------------------------------------------------------------
// row_start scan (3-phase)
// ---------------------------------------------------------------------------
__global__ void scan_phase1(const int* __restrict__ counts, int* __restrict__ rs,
                            int* __restrict__ block_sums)
{
    int b = blockIdx.x;
    int g = b / NCHUNK;
    int c = b - g * NCHUNK;
    int t = threadIdx.x;
    int i = c * 256 + t;
    __shared__ int sd[256];
    int v = (i < NN) ? counts[(size_t)g * NN + i] : 0;
    sd[t] = v;
    __syncthreads();
    for (int off = 1; off < 256; off <<= 1) {
        int x = (t >= off) ? sd[t - off] : 0;
        __syncthreads();
        sd[t] += x;
        __syncthreads();
    }
    if (i < NN) rs[(size_t)g * (NN + 1) + i] = sd[t] - v;
    if (t == 255) block_sums[b] = sd[255];
}

__global__ void scan_phase2(const int* __restrict__ block_sums,
                            int* __restrict__ chunk_off, int* __restrict__ rs)
{
    int g = blockIdx.x;
    int t = threadIdx.x;
    __shared__ int sd[256];
    int v = (t < NCHUNK) ? block_sums[g * NCHUNK + t] : 0;
    sd[t] = v;
    __syncthreads();
    for (int off = 1; off < 256; off <<= 1) {
        int x = (t >= off) ? sd[t - off] : 0;
        __syncthreads();
        sd[t] += x;
        __syncthreads();
    }
    if (t < NCHUNK) chunk_off[g * NCHUNK + t] = sd[t] - v;
    if (t == 255) rs[(size_t)g * (NN + 1) + NN] = sd[255];
}

__global__ void scan_phase3(int* __restrict__ rs, const int* __restrict__ chunk_off)
{
    int b = blockIdx.x;
    int g = b / NCHUNK;
    int c = b - g * NCHUNK;
    int i = c * 256 + threadIdx.x;
    if (i < NN) rs[(size_t)g * (NN + 1) + i] += chunk_off[g * NCHUNK + c];
}

// ---------------------------------------------------------------------------
// Staging-offset scan: 4704 entries, single block
// ---------------------------------------------------------------------------
__global__ void scan_stage_kernel(const int* __restrict__ cnt, int* __restrict__ off)
{
    __shared__ int sd[256];
    __shared__ int s_run;
    int t = threadIdx.x;
    if (t == 0) s_run = 0;
    __syncthreads();
    for (int base = 0; base < NSTAGE; base += 256) {
        int i = base + t;
        int v = (i < NSTAGE) ? cnt[i] : 0;
        sd[t] = v;
        __syncthreads();
        for (int o = 1; o < 256; o <<= 1) {
            int x = (t >= o) ? sd[t - o] : 0;
            __syncthreads();
            sd[t] += x;
            __syncthreads();
        }
        int run = s_run;
        __syncthreads();
        if (i < NSTAGE) off[i] = run + sd[t] - v;
        if (t == 255) s_run = run + sd[255];
        __syncthreads();
    }
}

// ---------------------------------------------------------------------------
// Phase A: bin edges into (g,bucket,slice) staging regions. One block = 4096
// consecutive edges of one graph -> slice uniform per block; appends within a
// slice come (mostly) from one XCD -> sector merging in its L2.
// ---------------------------------------------------------------------------
__global__ __launch_bounds__(256) void binA_kernel(
    const int* __restrict__ dst, const int* __restrict__ src,
    const float* __restrict__ e_edges, const int* __restrict__ stage_off,
    int* __restrict__ fill, uint2* __restrict__ staging)
{
    int blk = blockIdx.x;            // g * NBLK + bi
    int g = blk / NBLK;
    int bi = blk - g * NBLK;
    int base = bi * 4096;
    int slice = bi & 7;
    #pragma unroll 4
    for (int k = 0; k < 16; k++) {
        int e = base + k * 256 + threadIdx.x;
        if (e < EE) {
            int idxg = g * EE + e;
            int d = dst[idxg];
            int bucket = d >> 8;
            int sidx = ((g * NB + bucket) << 3) | slice;
            int pos = stage_off[sidx] + atomicAdd(&fill[sidx], 1);
            uint2 rec;
            rec.x = ((unsigned)f2bf(e_edges[idxg]) << 16) |
                    (unsigned)f2bf(e_edges[(size_t)(GG + g) * EE + e]);
            rec.y = ((unsigned)src[idxg] << 16) | (unsigned)(d & 255);
            staging[pos] = rec;
        }
    }
}

// ---------------------------------------------------------------------------
// Phase B: one block per (g,bucket). Segments are fully contained (bucket =
// 256 whole dst nodes). LDS hist+scan for CSR layout; LDS atomic max/sum for
// both layers' edge softmax; emit per-layer packed words (bf16 a)<<16|src
// into the bucket's contiguous output range (fully covered -> L2 merges).
// ---------------------------------------------------------------------------
__global__ __launch_bounds__(256) void bucket_kernel(
    const uint2* __restrict__ staging, const int* __restrict__ stage_off,
    const int* __restrict__ row_start, unsigned* __restrict__ packed0,
    unsigned* __restrict__ packed1)
{
    int blk = blockIdx.x;            // g * NB + bucket
    int g = blk / NB;
    int bucket = blk - g * NB;
    int bn = bucket << 8;
    int bnodes = min(256, NN - bn);
    const int* rs = row_start + (size_t)g * (NN + 1) + bn;
    int segStart = rs[0];
    int n = rs[bnodes] - segStart;
    int sbase = stage_off[(g * NB + bucket) << 3];   // bucket data contiguous

    __shared__ int hist[256];
    __shared__ int sd[256];
    __shared__ int cur[256];
    __shared__ unsigned mx[512];     // [0..255] layer0, [256..511] layer1
    __shared__ float sm[512];
    int t = threadIdx.x;
    hist[t] = 0;
    mx[t] = 0u; mx[256 + t] = 0u;
    sm[t] = 0.f; sm[256 + t] = 0.f;
    __syncthreads();

    // pass A: hist + per-node max (both layers)
    for (int i = t; i < n; i += 256) {
        uint2 r = staging[sbase + i];
        int dl = r.y & 0xff;
        atomicAdd(&hist[dl], 1);
        atomicMax(&mx[dl], fenc(bf2f(r.x >> 16)));
        atomicMax(&mx[256 + dl], fenc(bf2f(r.x & 0xffffu)));
    }
    __syncthreads();

    // exclusive scan of hist -> cur
    sd[t] = hist[t];
    __syncthreads();
    for (int o = 1; o < 256; o <<= 1) {
        int x = (t >= o) ? sd[t - o] : 0;
        __syncthreads();
        sd[t] += x;
        __syncthreads();
    }
    cur[t] = sd[t] - hist[t];
    __syncthreads();

    // pass B: exp-sums
    for (int i = t; i < n; i += 256) {
        uint2 r = staging[sbase + i];
        int dl = r.y & 0xff;
        atomicAdd(&sm[dl], __expf(bf2f(r.x >> 16) - fdec(mx[dl])));
        atomicAdd(&sm[256 + dl], __expf(bf2f(r.x & 0xffffu) - fdec(mx[256 + dl])));
    }
    __syncthreads();
    if (hist[t] > 0) {
        sm[t] = 1.f / sm[t];
        sm[256 + t] = 1.f / sm[256 + t];
    }
    __syncthreads();

    // pass C: emit packed words at CSR positions
    for (int i = t; i < n; i += 256) {
        uint2 r = staging[sbase + i];
        int dl = r.y & 0xff;
        unsigned srcv = r.y >> 16;
        int pos = atomicAdd(&cur[dl], 1);
        size_t o = (size_t)g * EE + segStart + pos;
        float a0 = __expf(bf2f(r.x >> 16) - fdec(mx[dl])) * sm[dl];
        float a1 = __expf(bf2f(r.x & 0xffffu) - fdec(mx[256 + dl])) * sm[256 + dl];
        packed0[o] = ((unsigned)f2bf(a0) << 16) | srcv;
        packed1[o] = ((unsigned)f2bf(a1) << 16) | srcv;
    }
}

// ---------------------------------------------------------------------------
// Batched gather-accumulate: 8 independent loads in flight per wave.
// Lanes past tE carry packed=0 (weight +0, row 0) -> self-masking.
// ---------------------------------------------------------------------------
__device__ __forceinline__ void consume8(unsigned packed, int cnt,
                                         const ushort* __restrict__ tab,
                                         int lane, float& acc)
{
    for (int k0 = 0; k0 < cnt; k0 += 8) {
        unsigned pk[8];
        #pragma unroll
        for (int u = 0; u < 8; u++) pk[u] = __shfl(packed, k0 + u);
        float vals[8];
        #pragma unroll
        for (int u = 0; u < 8; u++)
            vals[u] = bf2f((unsigned)tab[(size_t)(pk[u] & 0xffffu) * 64 + lane]);
        #pragma unroll
        for (int u = 0; u < 8; u++)
            acc = fmaf(vals[u], __uint_as_float(pk[u] & 0xffff0000u), acc);
    }
}

// ---------------------------------------------------------------------------
// Layer 0 propagation: wave per (g,node); weights pre-softmaxed in packed0.
// ---------------------------------------------------------------------------
__global__ __launch_bounds__(256) void prop0_kernel(
    const ushort* __restrict__ lab_bf, const float* __restrict__ labels_oh,
    const float* __restrict__ train_mask, const int* __restrict__ row_start,
    const unsigned* __restrict__ packed0, ushort* __restrict__ h_buf)
{
    int wid = (blockIdx.x * blockDim.x + threadIdx.x) >> 6;
    int lane = threadIdx.x & 63;
    if (wid >= GG * NN) return;
    int g = wid / NN;
    int v = wid - g * NN;
    const int* rs = row_start + (size_t)g * (NN + 1);
    int s = rs[v], tE = rs[v + 1];
    const unsigned* pk = packed0 + (size_t)g * EE;

    float acc = 0.f;
    for (int base = s; base < tE; base += 64) {
        int j = base + lane;
        unsigned packed = (j < tE) ? pk[j] : 0u;
        int cnt = min(64, tE - base);
        consume8(packed, cnt, lab_bf, lane, acc);
    }
    float tm = train_mask[v];
    float res = acc * (1.f - tm) + labels_oh[(size_t)v * 64 + lane] * tm;
    h_buf[(size_t)wid * 64 + lane] = f2bf(res);
}

// ---------------------------------------------------------------------------
// Layer 1 + attention combine + alpha mix: wave per node
// ---------------------------------------------------------------------------
__global__ __launch_bounds__(256) void final_kernel(
    const ushort* __restrict__ h_buf, const float* __restrict__ labels_oh,
    const float* __restrict__ train_mask, const float* __restrict__ attention,
    const float* __restrict__ alpha, const int* __restrict__ row_start,
    const unsigned* __restrict__ packed1, const float* __restrict__ out_ns,
    float* __restrict__ out_logits, float* __restrict__ out_lp)
{
    int wid = (blockIdx.x * blockDim.x + threadIdx.x) >> 6;
    int lane = threadIdx.x & 63;
    if (wid >= NN) return;
    int v = wid;
    float tm = train_mask[v];
    float ml = 1.f - tm;
    float moh = labels_oh[(size_t)v * 64 + lane] * tm;
    float a0 = attention[v * 3], a1 = attention[v * 3 + 1], a2 = attention[v * 3 + 2];
    float mxa = fmaxf(a0, fmaxf(a1, a2));
    float e0 = __expf(a0 - mxa), e1 = __expf(a1 - mxa), e2 = __expf(a2 - mxa);
    float ainv = 1.f / (e0 + e1 + e2);
    float attw[3] = {e0 * ainv, e1 * ainv, e2 * ainv};
    float lp = 0.f;
    #pragma unroll
    for (int g = 0; g < GG; g++) {
        const int* rs = row_start + (size_t)g * (NN + 1);
        int s = rs[v], tE = rs[v + 1];
        const unsigned* pk = packed1 + (size_t)g * EE;
        const ushort* hin = h_buf + (size_t)g * NN * 64;

        float acc = 0.f;
        for (int base = s; base < tE; base += 64) {
            int j = base + lane;
            unsigned packed = (j < tE) ? pk[j] : 0u;
            int cnt = min(64, tE - base);
            consume8(packed, cnt, hin, lane, acc);
        }
        float hf = acc * ml + moh;
        lp += attw[g] * hf;
    }
    size_t o = (size_t)v * 64 + lane;
    out_lp[o] = lp;
    float al = alpha[v];
    float sg = 1.f / (1.f + __expf(-al));
    out_logits[o] = sg * lp + (1.f - sg) * out_ns[o];
}

// ---------------------------------------------------------------------------
extern "C" void kernel_launch(void* const* d_in, const int* in_sizes, int n_in,
                              void* d_out, int out_size, void* d_ws, size_t ws_size,
                              hipStream_t stream)
{
    const float* features0  = (const float*)d_in[0];
    const float* label_init = (const float*)d_in[1];
    const float* labels_oh  = (const float*)d_in[2];
    const float* train_mask = (const float*)d_in[3];
    const int*   src        = (const int*)d_in[4];
    const int*   dst        = (const int*)d_in[5];
    const float* e_edges    = (const float*)d_in[6];
    const float* attention  = (const float*)d_in[7];
    const float* alpha      = (const float*)d_in[8];
    const float* W1         = (const float*)d_in[9];
    const float* b1         = (const float*)d_in[10];
    const float* W2         = (const float*)d_in[11];
    const float* b2         = (const float*)d_in[12];

    float* out        = (float*)d_out;
    float* out_logits = out;
    float* out_lp     = out + (size_t)NN * CC;
    float* out_ns     = out + 2 * (size_t)NN * CC;

    char* base = (char*)d_ws;
    size_t off = 0;
    auto alloc = [&](size_t bytes) -> void* {
        void* p = base + off;
        off = (off + bytes + 255) & ~(size_t)255;
        return p;
    };
    // zeroed-together block: counts + stage_cnt + fill (memset once)
    int*      counts     = (int*)alloc((size_t)GG * NN * sizeof(int));
    int*      stage_cnt  = (int*)alloc((size_t)NSTAGE * sizeof(int));
    int*      fill       = (int*)alloc((size_t)NSTAGE * sizeof(int));
    size_t    zero_bytes = off;
    int*      row_start  = (int*)alloc((size_t)GG * (NN + 1) * sizeof(int));
    int*      block_sums = (int*)alloc((size_t)GG * NCHUNK * sizeof(int));
    int*      chunk_off  = (int*)alloc((size_t)GG * NCHUNK * sizeof(int));
    int*      stage_off  = (int*)alloc((size_t)NSTAGE * sizeof(int));
    uint2*    staging    = (uint2*)alloc((size_t)GG * EE * sizeof(uint2));
    unsigned* packed0    = (unsigned*)alloc((size_t)GG * EE * sizeof(unsigned));
    unsigned* packed1    = (unsigned*)alloc((size_t)GG * EE * sizeof(unsigned));
    ushort*   h_buf      = (ushort*)alloc((size_t)GG * NN * CC * sizeof(ushort));
    ushort*   lab_bf     = (ushort*)alloc((size_t)NN * CC * sizeof(ushort));
    // hm (GEMM1 output, 51.2 MB) overlaps the front of ws; the MLP phase
    // completes (stream-ordered) before any CSR array is written -> safe.
    float* hm = (float*)d_ws;

    // ---- MLP: logits_ns = relu(features0 @ W1 + b1) @ W2 + b2 ----
    gemm_kernel<<<dim3((NN + 63) / 64, HH / 64), 256, 0, stream>>>(
        features0, W1, b1, hm, NN, HH, DD, 1);
    gemm_kernel<<<dim3((NN + 63) / 64, CC / 64), 256, 0, stream>>>(
        hm, W2, b2, out_ns, NN, CC, HH, 0);

    // ---- bf16 gather table for label_init ----
    cvt_kernel<<<(NN * CC / 4 + 255) / 256, 256, 0, stream>>>(
        label_init, lab_bf, NN * CC / 4);

    // ---- CSR build: hist -> scans -> bin -> per-bucket order+softmax ----
    hipMemsetAsync(counts, 0, zero_bytes, stream);
    hist_kernel<<<(GG * EE + 255) / 256, 256, 0, stream>>>(dst, counts, stage_cnt);
    scan_phase1<<<GG * NCHUNK, 256, 0, stream>>>(counts, row_start, block_sums);
    scan_phase2<<<GG, 256, 0, stream>>>(block_sums, chunk_off, row_start);
    scan_phase3<<<GG * NCHUNK, 256, 0, stream>>>(row_start, chunk_off);
    scan_stage_kernel<<<1, 256, 0, stream>>>(stage_cnt, stage_off);
    binA_kernel<<<GG * NBLK, 256, 0, stream>>>(
        dst, src, e_edges, stage_off, fill, staging);
    bucket_kernel<<<GG * NB, 256, 0, stream>>>(
        staging, stage_off, row_start, packed0, packed1);

    // ---- Layer 0 propagation ----
    prop0_kernel<<<((size_t)GG * NN * 64 + 255) / 256, 256, 0, stream>>>(
        lab_bf, labels_oh, train_mask, row_start, packed0, h_buf);

    // ---- Layer 1 + attention combine + alpha mix ----
    final_kernel<<<((size_t)NN * 64 + 255) / 256, 256, 0, stream>>>(
        h_buf, labels_oh, train_mask, attention, alpha, row_start, packed1,
        out_ns, out_logits, out_lp);
}

// Round 7
// 769.592 us; speedup vs baseline: 1.8219x; 1.8219x over previous
//
#include <hip/hip_runtime.h>
#include <hip/hip_bf16.h>

#define NN 50000
#define CC 64
#define GG 3
#define EE 1200000
#define LL 2
#define DD 256
#define HH 256
#define NCHUNK 196          // ceil(NN/256) for row_start scan
#define NB 196              // dst buckets of 256 nodes
#define NBLK 293            // ceil(EE/4096) edge chunks per graph

// Staged edge record (8B): x = bf16(e0)<<16 | bf16(e1); y = src<<16 | dst_local.
// Staging region for (g,bucket) = CSR range [rs[b*256], rs[(b+1)*256]) - exact.
// Final per-layer packed word (4B): bf16(a)<<16 | src  (src < 2^16).

__device__ __forceinline__ ushort f2bf(float f) {
    unsigned b = __float_as_uint(f);
    return (ushort)((b + 0x7fffu + ((b >> 16) & 1u)) >> 16);
}
__device__ __forceinline__ float bf2f(unsigned u) {
    return __uint_as_float(u << 16);
}
// order-preserving float<->uint for atomicMax
__device__ __forceinline__ unsigned fenc(float f) {
    unsigned u = __float_as_uint(f);
    return (u & 0x80000000u) ? ~u : (u | 0x80000000u);
}
__device__ __forceinline__ float fdec(unsigned u) {
    u = (u & 0x80000000u) ? (u & 0x7fffffffu) : ~u;
    return __uint_as_float(u);
}

// ---------------------------------------------------------------------------
// GEMM: C[M,Nc] = act(A[M,K] @ B[K,Nc] + bias), fp32, 64x64 tile, 4x4 micro
// ---------------------------------------------------------------------------
__global__ __launch_bounds__(256) void gemm_kernel(
    const float* __restrict__ A, const float* __restrict__ B,
    const float* __restrict__ bias, float* __restrict__ Cout,
    int M, int Nc, int K, int do_relu)
{
    __shared__ float As[16][68];
    __shared__ float Bs[16][64];
    int tid = threadIdx.x;
    int tx = tid & 15;
    int ty = tid >> 4;
    int m0 = blockIdx.x * 64;
    int n0 = blockIdx.y * 64;
    float acc[4][4] = {};

    for (int k0 = 0; k0 < K; k0 += 16) {
        {
            int kk = tid & 15;
            int mm = tid >> 4;
            #pragma unroll
            for (int i = 0; i < 4; i++) {
                int m = m0 + mm + i * 16;
                float v = (m < M) ? A[(size_t)m * K + k0 + kk] : 0.f;
                As[kk][mm + i * 16] = v;
            }
        }
        {
            int nn = tid & 63;
            int kk = tid >> 6;
            #pragma unroll
            for (int i = 0; i < 4; i++) {
                Bs[kk + i * 4][nn] = B[(size_t)(k0 + kk + i * 4) * Nc + n0 + nn];
            }
        }
        __syncthreads();
        #pragma unroll
        for (int kk = 0; kk < 16; kk++) {
            float4 a4 = *(const float4*)&As[kk][ty * 4];
            float4 b4 = *(const float4*)&Bs[kk][tx * 4];
            acc[0][0] += a4.x * b4.x; acc[0][1] += a4.x * b4.y;
            acc[0][2] += a4.x * b4.z; acc[0][3] += a4.x * b4.w;
            acc[1][0] += a4.y * b4.x; acc[1][1] += a4.y * b4.y;
            acc[1][2] += a4.y * b4.z; acc[1][3] += a4.y * b4.w;
            acc[2][0] += a4.z * b4.x; acc[2][1] += a4.z * b4.y;
            acc[2][2] += a4.z * b4.z; acc[2][3] += a4.z * b4.w;
            acc[3][0] += a4.w * b4.x; acc[3][1] += a4.w * b4.y;
            acc[3][2] += a4.w * b4.z; acc[3][3] += a4.w * b4.w;
        }
        __syncthreads();
    }
    #pragma unroll
    for (int i = 0; i < 4; i++) {
        int m = m0 + ty * 4 + i;
        if (m >= M) continue;
        #pragma unroll
        for (int j = 0; j < 4; j++) {
            int n = n0 + tx * 4 + j;
            float v = acc[i][j] + bias[n];
            if (do_relu) v = fmaxf(v, 0.f);
            Cout[(size_t)m * Nc + n] = v;
        }
    }
}

// ---------------------------------------------------------------------------
// fp32 -> bf16 table conversion (vectorized 4-wide)
// ---------------------------------------------------------------------------
__global__ void cvt_kernel(const float* __restrict__ in, ushort* __restrict__ out, int n4)
{
    int i = blockIdx.x * blockDim.x + threadIdx.x;
    if (i >= n4) return;
    float4 f = ((const float4*)in)[i];
    ushort4 u;
    u.x = f2bf(f.x); u.y = f2bf(f.y); u.z = f2bf(f.z); u.w = f2bf(f.w);
    ((ushort4*)out)[i] = u;
}

// ---------------------------------------------------------------------------
// Histogram: per-node counts only (150K addresses, ~24 hits each - cheap)
// ---------------------------------------------------------------------------
__global__ void hist_kernel(const int* __restrict__ dst, int* __restrict__ counts)
{
    int idx = blockIdx.x * blockDim.x + threadIdx.x;
    if (idx >= GG * EE) return;
    int g = idx / EE;
    atomicAdd(&counts[g * NN + dst[idx]], 1);
}

// ---------------------------------------------------------------------------
// row_start scan (3-phase)
// ---------------------------------------------------------------------------
__global__ void scan_phase1(const int* __restrict__ counts, int* __restrict__ rs,
                            int* __restrict__ block_sums)
{
    int b = blockIdx.x;
    int g = b / NCHUNK;
    int c = b - g * NCHUNK;
    int t = threadIdx.x;
    int i = c * 256 + t;
    __shared__ int sd[256];
    int v = (i < NN) ? counts[(size_t)g * NN + i] : 0;
    sd[t] = v;
    __syncthreads();
    for (int off = 1; off < 256; off <<= 1) {
        int x = (t >= off) ? sd[t - off] : 0;
        __syncthreads();
        sd[t] += x;
        __syncthreads();
    }
    if (i < NN) rs[(size_t)g * (NN + 1) + i] = sd[t] - v;
    if (t == 255) block_sums[b] = sd[255];
}

__global__ void scan_phase2(const int* __restrict__ block_sums,
                            int* __restrict__ chunk_off, int* __restrict__ rs)
{
    int g = blockIdx.x;
    int t = threadIdx.x;
    __shared__ int sd[256];
    int v = (t < NCHUNK) ? block_sums[g * NCHUNK + t] : 0;
    sd[t] = v;
    __syncthreads();
    for (int off = 1; off < 256; off <<= 1) {
        int x = (t >= off) ? sd[t - off] : 0;
        __syncthreads();
        sd[t] += x;
        __syncthreads();
    }
    if (t < NCHUNK) chunk_off[g * NCHUNK + t] = sd[t] - v;
    if (t == 255) rs[(size_t)g * (NN + 1) + NN] = sd[255];
}

__global__ void scan_phase3(int* __restrict__ rs, const int* __restrict__ chunk_off)
{
    int b = blockIdx.x;
    int g = b / NCHUNK;
    int c = b - g * NCHUNK;
    int i = c * 256 + threadIdx.x;
    if (i < NN) rs[(size_t)g * (NN + 1) + i] += chunk_off[g * NCHUNK + c];
}

// ---------------------------------------------------------------------------
// Phase A: bin edges into per-(g,bucket) staging regions (= their CSR ranges).
// One block = 4096 consecutive edges. LDS bucket histogram -> ONE global
// atomicAdd per (block,bucket) to reserve a contiguous run -> LDS-cursor
// scatter. Runs are contiguous (~170B) -> sectors merge. Global atomics:
// 879 x 196 = 172K total (vs 3.6M per-edge).
// ---------------------------------------------------------------------------
__global__ __launch_bounds__(256) void binA_kernel(
    const int* __restrict__ dst, const int* __restrict__ src,
    const float* __restrict__ e_edges, const int* __restrict__ row_start,
    int* __restrict__ fill, uint2* __restrict__ staging)
{
    int blk = blockIdx.x;            // g * NBLK + bi
    int g = blk / NBLK;
    int bi = blk - g * NBLK;
    int base = bi * 4096;
    __shared__ int cnt[NB];
    __shared__ int cur[NB];
    __shared__ int rbase[NB];
    int t = threadIdx.x;
    if (t < NB) cnt[t] = 0;
    __syncthreads();

    int myd[16];
    #pragma unroll
    for (int k = 0; k < 16; k++) {
        int e = base + k * 256 + t;
        int d = (e < EE) ? dst[g * EE + e] : -1;
        myd[k] = d;
        if (d >= 0) atomicAdd(&cnt[d >> 8], 1);
    }
    __syncthreads();
    if (t < NB) {
        int c = cnt[t];
        int b = (c > 0) ? atomicAdd(&fill[g * NB + t], c) : 0;
        rbase[t] = row_start[(size_t)g * (NN + 1) + (t << 8)];
        cur[t] = b;
    }
    __syncthreads();
    #pragma unroll
    for (int k = 0; k < 16; k++) {
        int d = myd[k];
        if (d >= 0) {
            int e = base + k * 256 + t;
            int bucket = d >> 8;
            int pos = rbase[bucket] + atomicAdd(&cur[bucket], 1);
            int idxg = g * EE + e;
            uint2 rec;
            rec.x = ((unsigned)f2bf(e_edges[idxg]) << 16) |
                    (unsigned)f2bf(e_edges[(size_t)(GG + g) * EE + e]);
            rec.y = ((unsigned)src[idxg] << 16) | (unsigned)(d & 255);
            staging[(size_t)g * EE + pos] = rec;
        }
    }
}

// ---------------------------------------------------------------------------
// Phase B: one block per (g,bucket). Reads its exact contiguous CSR range,
// LDS hist+scan for per-node layout, LDS atomic max/sum for both layers'
// softmax, emits packed words (bf16 a)<<16|src at CSR positions.
// ---------------------------------------------------------------------------
__global__ __launch_bounds__(256) void bucket_kernel(
    const uint2* __restrict__ staging, const int* __restrict__ row_start,
    unsigned* __restrict__ packed0, unsigned* __restrict__ packed1)
{
    int blk = blockIdx.x;            // g * NB + bucket
    int g = blk / NB;
    int bucket = blk - g * NB;
    int bn = bucket << 8;
    int bnodes = min(256, NN - bn);
    const int* rs = row_start + (size_t)g * (NN + 1) + bn;
    int segStart = rs[0];
    int n = rs[bnodes] - segStart;
    const uint2* st = staging + (size_t)g * EE + segStart;

    __shared__ int hist[256];
    __shared__ int sd[256];
    __shared__ int cur[256];
    __shared__ unsigned mx[512];     // [0..255] layer0, [256..511] layer1
    __shared__ float sm[512];
    int t = threadIdx.x;
    hist[t] = 0;
    mx[t] = 0u; mx[256 + t] = 0u;
    sm[t] = 0.f; sm[256 + t] = 0.f;
    __syncthreads();

    // pass A: hist + per-node max (both layers)
    for (int i = t; i < n; i += 256) {
        uint2 r = st[i];
        int dl = r.y & 0xff;
        atomicAdd(&hist[dl], 1);
        atomicMax(&mx[dl], fenc(bf2f(r.x >> 16)));
        atomicMax(&mx[256 + dl], fenc(bf2f(r.x & 0xffffu)));
    }
    __syncthreads();

    // exclusive scan of hist -> cur
    sd[t] = hist[t];
    __syncthreads();
    for (int o = 1; o < 256; o <<= 1) {
        int x = (t >= o) ? sd[t - o] : 0;
        __syncthreads();
        sd[t] += x;
        __syncthreads();
    }
    cur[t] = sd[t] - hist[t];
    __syncthreads();

    // pass B: exp-sums
    for (int i = t; i < n; i += 256) {
        uint2 r = st[i];
        int dl = r.y & 0xff;
        atomicAdd(&sm[dl], __expf(bf2f(r.x >> 16) - fdec(mx[dl])));
        atomicAdd(&sm[256 + dl], __expf(bf2f(r.x & 0xffffu) - fdec(mx[256 + dl])));
    }
    __syncthreads();
    if (hist[t] > 0) {
        sm[t] = 1.f / sm[t];
        sm[256 + t] = 1.f / sm[256 + t];
    }
    __syncthreads();

    // pass C: emit packed words at CSR positions
    for (int i = t; i < n; i += 256) {
        uint2 r = st[i];
        int dl = r.y & 0xff;
        unsigned srcv = r.y >> 16;
        int pos = atomicAdd(&cur[dl], 1);
        size_t o = (size_t)g * EE + segStart + pos;
        float a0 = __expf(bf2f(r.x >> 16) - fdec(mx[dl])) * sm[dl];
        float a1 = __expf(bf2f(r.x & 0xffffu) - fdec(mx[256 + dl])) * sm[256 + dl];
        packed0[o] = ((unsigned)f2bf(a0) << 16) | srcv;
        packed1[o] = ((unsigned)f2bf(a1) << 16) | srcv;
    }
}

// ---------------------------------------------------------------------------
// Batched gather-accumulate: 8 independent loads in flight per wave.
// Lanes past tE carry packed=0 (weight +0, row 0) -> self-masking.
// ---------------------------------------------------------------------------
__device__ __forceinline__ void consume8(unsigned packed, int cnt,
                                         const ushort* __restrict__ tab,
                                         int lane, float& acc)
{
    for (int k0 = 0; k0 < cnt; k0 += 8) {
        unsigned pk[8];
        #pragma unroll
        for (int u = 0; u < 8; u++) pk[u] = __shfl(packed, k0 + u);
        float vals[8];
        #pragma unroll
        for (int u = 0; u < 8; u++)
            vals[u] = bf2f((unsigned)tab[(size_t)(pk[u] & 0xffffu) * 64 + lane]);
        #pragma unroll
        for (int u = 0; u < 8; u++)
            acc = fmaf(vals[u], __uint_as_float(pk[u] & 0xffff0000u), acc);
    }
}

// ---------------------------------------------------------------------------
// Layer 0 propagation: wave per (g,node); weights pre-softmaxed in packed0.
// ---------------------------------------------------------------------------
__global__ __launch_bounds__(256) void prop0_kernel(
    const ushort* __restrict__ lab_bf, const float* __restrict__ labels_oh,
    const float* __restrict__ train_mask, const int* __restrict__ row_start,
    const unsigned* __restrict__ packed0, ushort* __restrict__ h_buf)
{
    int wid = (blockIdx.x * blockDim.x + threadIdx.x) >> 6;
    int lane = threadIdx.x & 63;
    if (wid >= GG * NN) return;
    int g = wid / NN;
    int v = wid - g * NN;
    const int* rs = row_start + (size_t)g * (NN + 1);
    int s = rs[v], tE = rs[v + 1];
    const unsigned* pk = packed0 + (size_t)g * EE;

    float acc = 0.f;
    for (int base = s; base < tE; base += 64) {
        int j = base + lane;
        unsigned packed = (j < tE) ? pk[j] : 0u;
        int cnt = min(64, tE - base);
        consume8(packed, cnt, lab_bf, lane, acc);
    }
    float tm = train_mask[v];
    float res = acc * (1.f - tm) + labels_oh[(size_t)v * 64 + lane] * tm;
    h_buf[(size_t)wid * 64 + lane] = f2bf(res);
}

// ---------------------------------------------------------------------------
// Layer 1 + attention combine + alpha mix: wave per node
// ---------------------------------------------------------------------------
__global__ __launch_bounds__(256) void final_kernel(
    const ushort* __restrict__ h_buf, const float* __restrict__ labels_oh,
    const float* __restrict__ train_mask, const float* __restrict__ attention,
    const float* __restrict__ alpha, const int* __restrict__ row_start,
    const unsigned* __restrict__ packed1, const float* __restrict__ out_ns,
    float* __restrict__ out_logits, float* __restrict__ out_lp)
{
    int wid = (blockIdx.x * blockDim.x + threadIdx.x) >> 6;
    int lane = threadIdx.x & 63;
    if (wid >= NN) return;
    int v = wid;
    float tm = train_mask[v];
    float ml = 1.f - tm;
    float moh = labels_oh[(size_t)v * 64 + lane] * tm;
    float a0 = attention[v * 3], a1 = attention[v * 3 + 1], a2 = attention[v * 3 + 2];
    float mxa = fmaxf(a0, fmaxf(a1, a2));
    float e0 = __expf(a0 - mxa), e1 = __expf(a1 - mxa), e2 = __expf(a2 - mxa);
    float ainv = 1.f / (e0 + e1 + e2);
    float attw[3] = {e0 * ainv, e1 * ainv, e2 * ainv};
    float lp = 0.f;
    #pragma unroll
    for (int g = 0; g < GG; g++) {
        const int* rs = row_start + (size_t)g * (NN + 1);
        int s = rs[v], tE = rs[v + 1];
        const unsigned* pk = packed1 + (size_t)g * EE;
        const ushort* hin = h_buf + (size_t)g * NN * 64;

        float acc = 0.f;
        for (int base = s; base < tE; base += 64) {
            int j = base + lane;
            unsigned packed = (j < tE) ? pk[j] : 0u;
            int cnt = min(64, tE - base);
            consume8(packed, cnt, hin, lane, acc);
        }
        float hf = acc * ml + moh;
        lp += attw[g] * hf;
    }
    size_t o = (size_t)v * 64 + lane;
    out_lp[o] = lp;
    float al = alpha[v];
    float sg = 1.f / (1.f + __expf(-al));
    out_logits[o] = sg * lp + (1.f - sg) * out_ns[o];
}

// ---------------------------------------------------------------------------
extern "C" void kernel_launch(void* const* d_in, const int* in_sizes, int n_in,
                              void* d_out, int out_size, void* d_ws, size_t ws_size,
                              hipStream_t stream)
{
    const float* features0  = (const float*)d_in[0];
    const float* label_init = (const float*)d_in[1];
    const float* labels_oh  = (const float*)d_in[2];
    const float* train_mask = (const float*)d_in[3];
    const int*   src        = (const int*)d_in[4];
    const int*   dst        = (const int*)d_in[5];
    const float* e_edges    = (const float*)d_in[6];
    const float* attention  = (const float*)d_in[7];
    const float* alpha      = (const float*)d_in[8];
    const float* W1         = (const float*)d_in[9];
    const float* b1         = (const float*)d_in[10];
    const float* W2         = (const float*)d_in[11];
    const float* b2         = (const float*)d_in[12];

    float* out        = (float*)d_out;
    float* out_logits = out;
    float* out_lp     = out + (size_t)NN * CC;
    float* out_ns     = out + 2 * (size_t)NN * CC;

    char* base = (char*)d_ws;
    size_t off = 0;
    auto alloc = [&](size_t bytes) -> void* {
        void* p = base + off;
        off = (off + bytes + 255) & ~(size_t)255;
        return p;
    };
    // zeroed-together block: counts + fill (one memset)
    int*      counts     = (int*)alloc((size_t)GG * NN * sizeof(int));
    int*      fill       = (int*)alloc((size_t)GG * NB * sizeof(int));
    size_t    zero_bytes = off;
    int*      row_start  = (int*)alloc((size_t)GG * (NN + 1) * sizeof(int));
    int*      block_sums = (int*)alloc((size_t)GG * NCHUNK * sizeof(int));
    int*      chunk_off  = (int*)alloc((size_t)GG * NCHUNK * sizeof(int));
    uint2*    staging    = (uint2*)alloc((size_t)GG * EE * sizeof(uint2));
    unsigned* packed0    = (unsigned*)alloc((size_t)GG * EE * sizeof(unsigned));
    unsigned* packed1    = (unsigned*)alloc((size_t)GG * EE * sizeof(unsigned));
    ushort*   h_buf      = (ushort*)alloc((size_t)GG * NN * CC * sizeof(ushort));
    ushort*   lab_bf     = (ushort*)alloc((size_t)NN * CC * sizeof(ushort));
    // hm (GEMM1 output, 51.2 MB) overlaps the front of ws; the MLP phase
    // completes (stream-ordered) before any CSR array is written -> safe.
    float* hm = (float*)d_ws;

    // ---- MLP: logits_ns = relu(features0 @ W1 + b1) @ W2 + b2 ----
    gemm_kernel<<<dim3((NN + 63) / 64, HH / 64), 256, 0, stream>>>(
        features0, W1, b1, hm, NN, HH, DD, 1);
    gemm_kernel<<<dim3((NN + 63) / 64, CC / 64), 256, 0, stream>>>(
        hm, W2, b2, out_ns, NN, CC, HH, 0);

    // ---- bf16 gather table for label_init ----
    cvt_kernel<<<(NN * CC / 4 + 255) / 256, 256, 0, stream>>>(
        label_init, lab_bf, NN * CC / 4);

    // ---- CSR build: hist -> scans -> LDS-aggregated bin -> bucket softmax --
    hipMemsetAsync(counts, 0, zero_bytes, stream);
    hist_kernel<<<(GG * EE + 255) / 256, 256, 0, stream>>>(dst, counts);
    scan_phase1<<<GG * NCHUNK, 256, 0, stream>>>(counts, row_start, block_sums);
    scan_phase2<<<GG, 256, 0, stream>>>(block_sums, chunk_off, row_start);
    scan_phase3<<<GG * NCHUNK, 256, 0, stream>>>(row_start, chunk_off);
    binA_kernel<<<GG * NBLK, 256, 0, stream>>>(
        dst, src, e_edges, row_start, fill, staging);
    bucket_kernel<<<GG * NB, 256, 0, stream>>>(
        staging, row_start, packed0, packed1);

    // ---- Layer 0 propagation ----
    prop0_kernel<<<((size_t)GG * NN * 64 + 255) / 256, 256, 0, stream>>>(
        lab_bf, labels_oh, train_mask, row_start, packed0, h_buf);

    // ---- Layer 1 + attention combine + alpha mix ----
    final_kernel<<<((size_t)NN * 64 + 255) / 256, 256, 0, stream>>>(
        h_buf, labels_oh, train_mask, attention, alpha, row_start, packed1,
        out_ns, out_logits, out_lp);
}

// Round 8
// 644.086 us; speedup vs baseline: 2.1769x; 1.1949x over previous
//
#include <hip/hip_runtime.h>
#include <hip/hip_bf16.h>

#define NN 50000
#define CC 64
#define GG 3
#define EE 1200000
#define LL 2
#define DD 256
#define HH 256
#define NB 196              // dst buckets of 256 nodes
#define NBLK 293            // ceil(EE/4096) edge chunks per graph
#define NBK (GG * NB)       // 588 (g,bucket) pairs

// Staged edge record (8B): x = bf16(e0)<<16 | bf16(e1); y = src<<16 | dst_local.
// Staging region for (g,bucket) = [bucket_start[idx], bucket_start[idx+1])
// (global across graphs; graph boundaries land at g*EE exactly).
// Final per-layer packed word (4B): bf16(a)<<16 | src  (src < 2^16).
// row_start is WRITTEN by bucket_kernel from its LDS scan (no global hist).

__device__ __forceinline__ ushort f2bf(float f) {
    unsigned b = __float_as_uint(f);
    return (ushort)((b + 0x7fffu + ((b >> 16) & 1u)) >> 16);
}
__device__ __forceinline__ float bf2f(unsigned u) {
    return __uint_as_float(u << 16);
}
// order-preserving float<->uint for atomicMax
__device__ __forceinline__ unsigned fenc(float f) {
    unsigned u = __float_as_uint(f);
    return (u & 0x80000000u) ? ~u : (u | 0x80000000u);
}
__device__ __forceinline__ float fdec(unsigned u) {
    u = (u & 0x80000000u) ? (u & 0x7fffffffu) : ~u;
    return __uint_as_float(u);
}

// ---------------------------------------------------------------------------
// GEMM: C[M,Nc] = act(A[M,K] @ B[K,Nc] + bias), fp32, 64x64 tile, 4x4 micro
// ---------------------------------------------------------------------------
__global__ __launch_bounds__(256) void gemm_kernel(
    const float* __restrict__ A, const float* __restrict__ B,
    const float* __restrict__ bias, float* __restrict__ Cout,
    int M, int Nc, int K, int do_relu)
{
    __shared__ float As[16][68];
    __shared__ float Bs[16][64];
    int tid = threadIdx.x;
    int tx = tid & 15;
    int ty = tid >> 4;
    int m0 = blockIdx.x * 64;
    int n0 = blockIdx.y * 64;
    float acc[4][4] = {};

    for (int k0 = 0; k0 < K; k0 += 16) {
        {
            int kk = tid & 15;
            int mm = tid >> 4;
            #pragma unroll
            for (int i = 0; i < 4; i++) {
                int m = m0 + mm + i * 16;
                float v = (m < M) ? A[(size_t)m * K + k0 + kk] : 0.f;
                As[kk][mm + i * 16] = v;
            }
        }
        {
            int nn = tid & 63;
            int kk = tid >> 6;
            #pragma unroll
            for (int i = 0; i < 4; i++) {
                Bs[kk + i * 4][nn] = B[(size_t)(k0 + kk + i * 4) * Nc + n0 + nn];
            }
        }
        __syncthreads();
        #pragma unroll
        for (int kk = 0; kk < 16; kk++) {
            float4 a4 = *(const float4*)&As[kk][ty * 4];
            float4 b4 = *(const float4*)&Bs[kk][tx * 4];
            acc[0][0] += a4.x * b4.x; acc[0][1] += a4.x * b4.y;
            acc[0][2] += a4.x * b4.z; acc[0][3] += a4.x * b4.w;
            acc[1][0] += a4.y * b4.x; acc[1][1] += a4.y * b4.y;
            acc[1][2] += a4.y * b4.z; acc[1][3] += a4.y * b4.w;
            acc[2][0] += a4.z * b4.x; acc[2][1] += a4.z * b4.y;
            acc[2][2] += a4.z * b4.z; acc[2][3] += a4.z * b4.w;
            acc[3][0] += a4.w * b4.x; acc[3][1] += a4.w * b4.y;
            acc[3][2] += a4.w * b4.z; acc[3][3] += a4.w * b4.w;
        }
        __syncthreads();
    }
    #pragma unroll
    for (int i = 0; i < 4; i++) {
        int m = m0 + ty * 4 + i;
        if (m >= M) continue;
        #pragma unroll
        for (int j = 0; j < 4; j++) {
            int n = n0 + tx * 4 + j;
            float v = acc[i][j] + bias[n];
            if (do_relu) v = fmaxf(v, 0.f);
            Cout[(size_t)m * Nc + n] = v;
        }
    }
}

// ---------------------------------------------------------------------------
// fp32 -> bf16 table conversion (vectorized 4-wide)
// ---------------------------------------------------------------------------
__global__ void cvt_kernel(const float* __restrict__ in, ushort* __restrict__ out, int n4)
{
    int i = blockIdx.x * blockDim.x + threadIdx.x;
    if (i >= n4) return;
    float4 f = ((const float4*)in)[i];
    ushort4 u;
    u.x = f2bf(f.x); u.y = f2bf(f.y); u.z = f2bf(f.z); u.w = f2bf(f.w);
    ((ushort4*)out)[i] = u;
}

// ---------------------------------------------------------------------------
// Bucket-level histogram: LDS 196 counters per block, ONE global atomic per
// (block,bucket). 879*196 = 172K atomics on 588 addresses (vs 3.6M on 150K).
// ---------------------------------------------------------------------------
__global__ __launch_bounds__(256) void bhist_kernel(
    const int* __restrict__ dst, int* __restrict__ bcnt)
{
    int blk = blockIdx.x;            // g * NBLK + bi
    int g = blk / NBLK;
    int bi = blk - g * NBLK;
    int base = bi * 4096;
    __shared__ int cnt[NB];
    int t = threadIdx.x;
    if (t < NB) cnt[t] = 0;
    __syncthreads();
    #pragma unroll
    for (int k = 0; k < 16; k++) {
        int e = base + k * 256 + t;
        if (e < EE) atomicAdd(&cnt[dst[g * EE + e] >> 8], 1);
    }
    __syncthreads();
    if (t < NB && cnt[t] > 0) atomicAdd(&bcnt[g * NB + t], cnt[t]);
}

// ---------------------------------------------------------------------------
// Scan 588 bucket counts -> bucket_start (global staging offsets) + sentinel
// ---------------------------------------------------------------------------
__global__ void scan_bucket(const int* __restrict__ bcnt, int* __restrict__ bs)
{
    __shared__ int sd[256];
    __shared__ int s_run;
    int t = threadIdx.x;
    if (t == 0) s_run = 0;
    __syncthreads();
    for (int base = 0; base < NBK; base += 256) {
        int i = base + t;
        int v = (i < NBK) ? bcnt[i] : 0;
        sd[t] = v;
        __syncthreads();
        for (int o = 1; o < 256; o <<= 1) {
            int x = (t >= o) ? sd[t - o] : 0;
            __syncthreads();
            sd[t] += x;
            __syncthreads();
        }
        int run = s_run;
        __syncthreads();
        if (i < NBK) bs[i] = run + sd[t] - v;
        if (t == 255) s_run = run + sd[255];
        __syncthreads();
    }
    if (t == 0) bs[NBK] = GG * EE;
}

// ---------------------------------------------------------------------------
// Phase A: bin edges into per-(g,bucket) staging regions. One block = 4096
// consecutive edges. LDS bucket histogram -> ONE global atomicAdd per
// (block,bucket) -> LDS-cursor scatter; runs contiguous -> sectors merge.
// ---------------------------------------------------------------------------
__global__ __launch_bounds__(256) void binA_kernel(
    const int* __restrict__ dst, const int* __restrict__ src,
    const float* __restrict__ e_edges, const int* __restrict__ bucket_start,
    int* __restrict__ fill, uint2* __restrict__ staging)
{
    int blk = blockIdx.x;            // g * NBLK + bi
    int g = blk / NBLK;
    int bi = blk - g * NBLK;
    int base = bi * 4096;
    __shared__ int cnt[NB];
    __shared__ int cur[NB];
    __shared__ int rbase[NB];
    int t = threadIdx.x;
    if (t < NB) cnt[t] = 0;
    __syncthreads();

    int myd[16];
    #pragma unroll
    for (int k = 0; k < 16; k++) {
        int e = base + k * 256 + t;
        int d = (e < EE) ? dst[g * EE + e] : -1;
        myd[k] = d;
        if (d >= 0) atomicAdd(&cnt[d >> 8], 1);
    }
    __syncthreads();
    if (t < NB) {
        int c = cnt[t];
        int b = (c > 0) ? atomicAdd(&fill[g * NB + t], c) : 0;
        rbase[t] = bucket_start[g * NB + t];
        cur[t] = b;
    }
    __syncthreads();
    #pragma unroll
    for (int k = 0; k < 16; k++) {
        int d = myd[k];
        if (d >= 0) {
            int e = base + k * 256 + t;
            int bucket = d >> 8;
            int pos = rbase[bucket] + atomicAdd(&cur[bucket], 1);
            int idxg = g * EE + e;
            uint2 rec;
            rec.x = ((unsigned)f2bf(e_edges[idxg]) << 16) |
                    (unsigned)f2bf(e_edges[(size_t)(GG + g) * EE + e]);
            rec.y = ((unsigned)src[idxg] << 16) | (unsigned)(d & 255);
            staging[pos] = rec;
        }
    }
}

// ---------------------------------------------------------------------------
// Phase B: one block per (g,bucket). Reads its contiguous staging range,
// LDS hist+scan for per-node layout (also WRITES row_start), LDS atomic
// max/sum for both layers' softmax, emits packed words at CSR positions.
// ---------------------------------------------------------------------------
__global__ __launch_bounds__(256) void bucket_kernel(
    const uint2* __restrict__ staging, const int* __restrict__ bucket_start,
    int* __restrict__ row_start, unsigned* __restrict__ packed0,
    unsigned* __restrict__ packed1)
{
    int blk = blockIdx.x;            // g * NB + bucket
    int g = blk / NB;
    int bucket = blk - g * NB;
    int bn = bucket << 8;
    int bnodes = min(256, NN - bn);
    int sbase = bucket_start[blk];           // global staging index
    int n = bucket_start[blk + 1] - sbase;
    int segStart = sbase - g * EE;           // CSR offset within graph
    const uint2* st = staging + sbase;

    __shared__ int hist[256];
    __shared__ int sd[256];
    __shared__ int cur[256];
    __shared__ unsigned mx[512];     // [0..255] layer0, [256..511] layer1
    __shared__ float sm[512];
    int t = threadIdx.x;
    hist[t] = 0;
    mx[t] = 0u; mx[256 + t] = 0u;
    sm[t] = 0.f; sm[256 + t] = 0.f;
    __syncthreads();

    // pass A: hist + per-node max (both layers)
    for (int i = t; i < n; i += 256) {
        uint2 r = st[i];
        int dl = r.y & 0xff;
        atomicAdd(&hist[dl], 1);
        atomicMax(&mx[dl], fenc(bf2f(r.x >> 16)));
        atomicMax(&mx[256 + dl], fenc(bf2f(r.x & 0xffffu)));
    }
    __syncthreads();

    // exclusive scan of hist -> cur; also publish row_start
    sd[t] = hist[t];
    __syncthreads();
    for (int o = 1; o < 256; o <<= 1) {
        int x = (t >= o) ? sd[t - o] : 0;
        __syncthreads();
        sd[t] += x;
        __syncthreads();
    }
    cur[t] = sd[t] - hist[t];
    if (t < bnodes) row_start[(size_t)g * (NN + 1) + bn + t] = segStart + sd[t] - hist[t];
    if (bucket == NB - 1 && t == 0) row_start[(size_t)g * (NN + 1) + NN] = EE;
    __syncthreads();

    // pass B: exp-sums
    for (int i = t; i < n; i += 256) {
        uint2 r = st[i];
        int dl = r.y & 0xff;
        atomicAdd(&sm[dl], __expf(bf2f(r.x >> 16) - fdec(mx[dl])));
        atomicAdd(&sm[256 + dl], __expf(bf2f(r.x & 0xffffu) - fdec(mx[256 + dl])));
    }
    __syncthreads();
    if (hist[t] > 0) {
        sm[t] = 1.f / sm[t];
        sm[256 + t] = 1.f / sm[256 + t];
    }
    __syncthreads();

    // pass C: emit packed words at CSR positions
    for (int i = t; i < n; i += 256) {
        uint2 r = st[i];
        int dl = r.y & 0xff;
        unsigned srcv = r.y >> 16;
        int pos = atomicAdd(&cur[dl], 1);
        size_t o = (size_t)sbase + pos;      // == g*EE + segStart + pos
        float a0 = __expf(bf2f(r.x >> 16) - fdec(mx[dl])) * sm[dl];
        float a1 = __expf(bf2f(r.x & 0xffffu) - fdec(mx[256 + dl])) * sm[256 + dl];
        packed0[o] = ((unsigned)f2bf(a0) << 16) | srcv;
        packed1[o] = ((unsigned)f2bf(a1) << 16) | srcv;
    }
}

// ---------------------------------------------------------------------------
// Batched gather-accumulate: 8 independent loads in flight per wave.
// Lanes past tE carry packed=0 (weight +0, row 0) -> self-masking.
// ---------------------------------------------------------------------------
__device__ __forceinline__ void consume8(unsigned packed, int cnt,
                                         const ushort* __restrict__ tab,
                                         int lane, float& acc)
{
    for (int k0 = 0; k0 < cnt; k0 += 8) {
        unsigned pk[8];
        #pragma unroll
        for (int u = 0; u < 8; u++) pk[u] = __shfl(packed, k0 + u);
        float vals[8];
        #pragma unroll
        for (int u = 0; u < 8; u++)
            vals[u] = bf2f((unsigned)tab[(size_t)(pk[u] & 0xffffu) * 64 + lane]);
        #pragma unroll
        for (int u = 0; u < 8; u++)
            acc = fmaf(vals[u], __uint_as_float(pk[u] & 0xffff0000u), acc);
    }
}

// ---------------------------------------------------------------------------
// Layer 0 propagation: wave per (g,node); weights pre-softmaxed in packed0.
// ---------------------------------------------------------------------------
__global__ __launch_bounds__(256) void prop0_kernel(
    const ushort* __restrict__ lab_bf, const float* __restrict__ labels_oh,
    const float* __restrict__ train_mask, const int* __restrict__ row_start,
    const unsigned* __restrict__ packed0, ushort* __restrict__ h_buf)
{
    int wid = (blockIdx.x * blockDim.x + threadIdx.x) >> 6;
    int lane = threadIdx.x & 63;
    if (wid >= GG * NN) return;
    int g = wid / NN;
    int v = wid - g * NN;
    const int* rs = row_start + (size_t)g * (NN + 1);
    int s = rs[v], tE = rs[v + 1];
    const unsigned* pk = packed0 + (size_t)g * EE;

    float acc = 0.f;
    for (int base = s; base < tE; base += 64) {
        int j = base + lane;
        unsigned packed = (j < tE) ? pk[j] : 0u;
        int cnt = min(64, tE - base);
        consume8(packed, cnt, lab_bf, lane, acc);
    }
    float tm = train_mask[v];
    float res = acc * (1.f - tm) + labels_oh[(size_t)v * 64 + lane] * tm;
    h_buf[(size_t)wid * 64 + lane] = f2bf(res);
}

// ---------------------------------------------------------------------------
// Layer 1 + attention combine + alpha mix: wave per node
// ---------------------------------------------------------------------------
__global__ __launch_bounds__(256) void final_kernel(
    const ushort* __restrict__ h_buf, const float* __restrict__ labels_oh,
    const float* __restrict__ train_mask, const float* __restrict__ attention,
    const float* __restrict__ alpha, const int* __restrict__ row_start,
    const unsigned* __restrict__ packed1, const float* __restrict__ out_ns,
    float* __restrict__ out_logits, float* __restrict__ out_lp)
{
    int wid = (blockIdx.x * blockDim.x + threadIdx.x) >> 6;
    int lane = threadIdx.x & 63;
    if (wid >= NN) return;
    int v = wid;
    float tm = train_mask[v];
    float ml = 1.f - tm;
    float moh = labels_oh[(size_t)v * 64 + lane] * tm;
    float a0 = attention[v * 3], a1 = attention[v * 3 + 1], a2 = attention[v * 3 + 2];
    float mxa = fmaxf(a0, fmaxf(a1, a2));
    float e0 = __expf(a0 - mxa), e1 = __expf(a1 - mxa), e2 = __expf(a2 - mxa);
    float ainv = 1.f / (e0 + e1 + e2);
    float attw[3] = {e0 * ainv, e1 * ainv, e2 * ainv};
    float lp = 0.f;
    #pragma unroll
    for (int g = 0; g < GG; g++) {
        const int* rs = row_start + (size_t)g * (NN + 1);
        int s = rs[v], tE = rs[v + 1];
        const unsigned* pk = packed1 + (size_t)g * EE;
        const ushort* hin = h_buf + (size_t)g * NN * 64;

        float acc = 0.f;
        for (int base = s; base < tE; base += 64) {
            int j = base + lane;
            unsigned packed = (j < tE) ? pk[j] : 0u;
            int cnt = min(64, tE - base);
            consume8(packed, cnt, hin, lane, acc);
        }
        float hf = acc * ml + moh;
        lp += attw[g] * hf;
    }
    size_t o = (size_t)v * 64 + lane;
    out_lp[o] = lp;
    float al = alpha[v];
    float sg = 1.f / (1.f + __expf(-al));
    out_logits[o] = sg * lp + (1.f - sg) * out_ns[o];
}

// ---------------------------------------------------------------------------
extern "C" void kernel_launch(void* const* d_in, const int* in_sizes, int n_in,
                              void* d_out, int out_size, void* d_ws, size_t ws_size,
                              hipStream_t stream)
{
    const float* features0  = (const float*)d_in[0];
    const float* label_init = (const float*)d_in[1];
    const float* labels_oh  = (const float*)d_in[2];
    const float* train_mask = (const float*)d_in[3];
    const int*   src        = (const int*)d_in[4];
    const int*   dst        = (const int*)d_in[5];
    const float* e_edges    = (const float*)d_in[6];
    const float* attention  = (const float*)d_in[7];
    const float* alpha      = (const float*)d_in[8];
    const float* W1         = (const float*)d_in[9];
    const float* b1         = (const float*)d_in[10];
    const float* W2         = (const float*)d_in[11];
    const float* b2         = (const float*)d_in[12];

    float* out        = (float*)d_out;
    float* out_logits = out;
    float* out_lp     = out + (size_t)NN * CC;
    float* out_ns     = out + 2 * (size_t)NN * CC;

    char* base = (char*)d_ws;
    size_t off = 0;
    auto alloc = [&](size_t bytes) -> void* {
        void* p = base + off;
        off = (off + bytes + 255) & ~(size_t)255;
        return p;
    };
    // zeroed-together block: bcnt + fill (one tiny memset)
    int*      bcnt         = (int*)alloc((size_t)NBK * sizeof(int));
    int*      fill         = (int*)alloc((size_t)NBK * sizeof(int));
    size_t    zero_bytes   = off;
    int*      bucket_start = (int*)alloc((size_t)(NBK + 1) * sizeof(int));
    int*      row_start    = (int*)alloc((size_t)GG * (NN + 1) * sizeof(int));
    uint2*    staging      = (uint2*)alloc((size_t)GG * EE * sizeof(uint2));
    unsigned* packed0      = (unsigned*)alloc((size_t)GG * EE * sizeof(unsigned));
    unsigned* packed1      = (unsigned*)alloc((size_t)GG * EE * sizeof(unsigned));
    ushort*   h_buf        = (ushort*)alloc((size_t)GG * NN * CC * sizeof(ushort));
    ushort*   lab_bf       = (ushort*)alloc((size_t)NN * CC * sizeof(ushort));
    // hm (GEMM1 output, 51.2 MB) overlaps the front of ws; all overlapping
    // writes are stream-ordered after gemm2 (hm's last reader) -> safe.
    float* hm = (float*)d_ws;

    // ---- MLP: logits_ns = relu(features0 @ W1 + b1) @ W2 + b2 ----
    gemm_kernel<<<dim3((NN + 63) / 64, HH / 64), 256, 0, stream>>>(
        features0, W1, b1, hm, NN, HH, DD, 1);
    gemm_kernel<<<dim3((NN + 63) / 64, CC / 64), 256, 0, stream>>>(
        hm, W2, b2, out_ns, NN, CC, HH, 0);

    // ---- bf16 gather table for label_init ----
    cvt_kernel<<<(NN * CC / 4 + 255) / 256, 256, 0, stream>>>(
        label_init, lab_bf, NN * CC / 4);

    // ---- CSR build: bucket hist -> tiny scan -> LDS-aggregated bin ->
    //      per-bucket order + softmax (writes row_start itself) ----
    hipMemsetAsync(bcnt, 0, zero_bytes, stream);
    bhist_kernel<<<GG * NBLK, 256, 0, stream>>>(dst, bcnt);
    scan_bucket<<<1, 256, 0, stream>>>(bcnt, bucket_start);
    binA_kernel<<<GG * NBLK, 256, 0, stream>>>(
        dst, src, e_edges, bucket_start, fill, staging);
    bucket_kernel<<<GG * NB, 256, 0, stream>>>(
        staging, bucket_start, row_start, packed0, packed1);

    // ---- Layer 0 propagation ----
    prop0_kernel<<<((size_t)GG * NN * 64 + 255) / 256, 256, 0, stream>>>(
        lab_bf, labels_oh, train_mask, row_start, packed0, h_buf);

    // ---- Layer 1 + attention combine + alpha mix ----
    final_kernel<<<((size_t)NN * 64 + 255) / 256, 256, 0, stream>>>(
        h_buf, labels_oh, train_mask, attention, alpha, row_start, packed1,
        out_ns, out_logits, out_lp);
}